// Round 3
// baseline (598.807 us; speedup 1.0000x reference)
//
#include <hip/hip_runtime.h>

// Problem constants
#define NPX   131072      // B*H*W = 32*64*64 pixels
#define CHN   128         // NUM_HIDDENS
#define HWN   4096        // H*W
#define EMB   64
#define NCODE 512

// ws layout (bytes)
#define WS_HIST 0         // 512 * u32
#define WS_LOSS 2048      // 1 * f32
#define WS_CC   4096      // 512 * f32
#define WS_PWT  8192      // 128*64 f32 (pre_w transposed, 32 KB)
#define WS_IDX  40960     // 131072 * i32 (512 KB)

// Scratch carved out of the decode-output region (out+1 .. out+16777216),
// which vq_decode fully overwrites at the end:
//   zbuf  = out + 8         : 8388608 f32 (z, [pixel][64]) -- 16B aligned
//   bestb = out + 8388616   : 524288 f32  (per-chunk best dist, [pixel][4])
//   bidxb = out + 8912904   : 524288 i32  (per-chunk best idx,  [pixel][4])

// --- prep: transpose pre_w to [c][d]; cc[k] = sum_d cb[k][d]^2 (pairwise-8).
__global__ __launch_bounds__(512) void vq_prep(const float* __restrict__ preW,
                                               const float* __restrict__ cb,
                                               float* __restrict__ preWT,
                                               float* __restrict__ cc) {
  int t = threadIdx.x;
  for (int i = t; i < CHN * EMB; i += 512) {
    int c = i >> 6, d = i & 63;
    preWT[i] = preW[d * CHN + c];   // preW is [64][128]
  }
  if (t < NCODE) {
    const float* row = cb + t * EMB;
    float r[8];
#pragma unroll
    for (int j = 0; j < 8; ++j) r[j] = __fmul_rn(row[j], row[j]);
#pragma unroll
    for (int b = 1; b < 8; ++b)
#pragma unroll
      for (int j = 0; j < 8; ++j)
        r[j] = __fadd_rn(r[j], __fmul_rn(row[b * 8 + j], row[b * 8 + j]));
    cc[t] = __fadd_rn(__fadd_rn(__fadd_rn(r[0], r[1]), __fadd_rn(r[2], r[3])),
                      __fadd_rn(__fadd_rn(r[4], r[5]), __fadd_rn(r[6], r[7])));
  }
}

// ===================== vq_pre =====================
// z[p][d] = sum_c A[b,c,hw]*preW[d,c] + preB[d], d split in halves (grid 1024).
// Weights staged in LDS, read as uniform ds_read_b128 into 4 rotating
// half-row buffers (prefetch distance 4 phases). A prefetched 2 groups ahead
// via two alternating register sets. Per-z[d] accumulation order: c ascending,
// unfused mul+add — identical to the round-0/1 passing versions.

#define PRE_ALOAD(AA, CB) { \
  AA[0] = Ab[(size_t)(((CB) + 0) & 127) * HWN]; \
  AA[1] = Ab[(size_t)(((CB) + 1) & 127) * HWN]; \
  AA[2] = Ab[(size_t)(((CB) + 2) & 127) * HWN]; \
  AA[3] = Ab[(size_t)(((CB) + 3) & 127) * HWN]; }

#define PRE_HALF(av, WB, ZOFF) { \
  _Pragma("unroll") \
  for (int j = 0; j < 4; ++j) { \
    float4 w = WB[j]; \
    z[(ZOFF) + 4*j + 0] = __fadd_rn(z[(ZOFF) + 4*j + 0], __fmul_rn(av, w.x)); \
    z[(ZOFF) + 4*j + 1] = __fadd_rn(z[(ZOFF) + 4*j + 1], __fmul_rn(av, w.y)); \
    z[(ZOFF) + 4*j + 2] = __fadd_rn(z[(ZOFF) + 4*j + 2], __fmul_rn(av, w.z)); \
    z[(ZOFF) + 4*j + 3] = __fadd_rn(z[(ZOFF) + 4*j + 3], __fmul_rn(av, w.w)); } }

#define PRE_WLOAD(WB, C, HOFF) { \
  int cw_ = (C) & 127; \
  _Pragma("unroll") \
  for (int j = 0; j < 4; ++j) WB[j] = sw[cw_ * 8 + (HOFF) + j]; }

// one 4-c group: entry invariant W0=H(CB,0) W1=H(CB,1) W2=H(CB+1,0) W3=H(CB+1,1)
#define PRE_GROUP(AA, CB) { \
  PRE_HALF(AA[0], W0, 0)  PRE_WLOAD(W0, (CB) + 2, 0) \
  PRE_HALF(AA[0], W1, 16) PRE_WLOAD(W1, (CB) + 2, 4) \
  PRE_HALF(AA[1], W2, 0)  PRE_WLOAD(W2, (CB) + 3, 0) \
  PRE_HALF(AA[1], W3, 16) PRE_WLOAD(W3, (CB) + 3, 4) \
  PRE_HALF(AA[2], W0, 0)  PRE_WLOAD(W0, (CB) + 4, 0) \
  PRE_HALF(AA[2], W1, 16) PRE_WLOAD(W1, (CB) + 4, 4) \
  PRE_HALF(AA[3], W2, 0)  PRE_WLOAD(W2, (CB) + 5, 0) \
  PRE_HALF(AA[3], W3, 16) PRE_WLOAD(W3, (CB) + 5, 4) }

__global__ __launch_bounds__(256) void vq_pre(const float* __restrict__ A,
                                              const float* __restrict__ preWT,
                                              const float* __restrict__ preB,
                                              float* __restrict__ zbuf) {
  __shared__ float4 sw[1024];   // [c=128][8 f4] = w[c][d0..d0+31], 16 KB
  __shared__ float sb[32];
  int bid = blockIdx.x;
  int ph = bid & 511, dh = bid >> 9;
  int d0 = dh << 5;
  int p = ph * 256 + threadIdx.x;
  int b = p >> 12, hw = p & 4095;
  const float* Ab = A + (size_t)b * CHN * HWN + hw;

  for (int i = threadIdx.x; i < 1024; i += 256) {
    int c = i >> 3, j = i & 7;
    sw[i] = *((const float4*)(preWT + c * EMB + d0) + j);
  }
  if (threadIdx.x < 32) sb[threadIdx.x] = preB[d0 + threadIdx.x];
  __syncthreads();

  float z[32];
#pragma unroll
  for (int d = 0; d < 32; ++d) z[d] = 0.f;

  float aA[4], aB[4];
  PRE_ALOAD(aA, 0)
  PRE_ALOAD(aB, 4)

  float4 W0[4], W1[4], W2[4], W3[4];
#pragma unroll
  for (int j = 0; j < 4; ++j) { W0[j] = sw[j]; W1[j] = sw[4 + j]; W2[j] = sw[8 + j]; W3[j] = sw[12 + j]; }

#pragma unroll 1
  for (int g2 = 0; g2 < 16; ++g2) {
    int c0 = g2 * 8;
    PRE_GROUP(aA, c0)          // consume c0..c0+3
    PRE_ALOAD(aA, c0 + 8)      // prefetch next iteration's first group
    PRE_GROUP(aB, c0 + 4)      // consume c0+4..c0+7
    PRE_ALOAD(aB, c0 + 12)     // prefetch next iteration's second group
  }

#pragma unroll
  for (int d = 0; d < 32; ++d) z[d] = __fadd_rn(z[d], sb[d]);

  float4* zp = (float4*)(zbuf + (size_t)p * 64 + d0);
#pragma unroll
  for (int i = 0; i < 8; ++i)
    zp[i] = make_float4(z[4 * i + 0], z[4 * i + 1], z[4 * i + 2], z[4 * i + 3]);
}

// ===================== vq_search =====================
// Split-K (4 chunks of 128 codes). Code chunk staged in LDS (32 KB), read as
// uniform ds_read_b128 into 4 rotating quarter-row buffers. Dist arithmetic,
// accumulation order, and strict-< ascending-k tie-break identical.

#define SRCH_Q(WB, ZOFF) { \
  _Pragma("unroll") \
  for (int j = 0; j < 4; ++j) { \
    float4 c4 = WB[j]; \
    d0 = fmaf(c4.x, z[(ZOFF) + 4*j + 0], d0); \
    d1 = fmaf(c4.y, z[(ZOFF) + 4*j + 1], d1); \
    d2 = fmaf(c4.z, z[(ZOFF) + 4*j + 2], d2); \
    d3 = fmaf(c4.w, z[(ZOFF) + 4*j + 3], d3); } }

#define SRCH_L(WB, OFF) { \
  _Pragma("unroll") \
  for (int j = 0; j < 4; ++j) WB[j] = nx[(OFF) + j]; }

__global__ __launch_bounds__(256) void vq_search(const float* __restrict__ zbuf,
                                                 const float* __restrict__ cb,
                                                 const float* __restrict__ cc,
                                                 float* __restrict__ bestb,
                                                 int* __restrict__ bidxb) {
  __shared__ float4 sc[2048];   // 128 codes * 16 f4 = 32 KB
  __shared__ float scc[128];
  int bid = blockIdx.x;
  int q = bid & 3, ph = bid >> 2;
  int p = ph * 256 + threadIdx.x;
  int k0 = q << 7;

  // z gather (independent global loads — issued before LDS staging)
  float z[64];
  const float4* z4 = (const float4*)(zbuf + (size_t)p * 64);
#pragma unroll
  for (int i = 0; i < 16; ++i) {
    float4 v = z4[i];
    z[4 * i + 0] = v.x; z[4 * i + 1] = v.y; z[4 * i + 2] = v.z; z[4 * i + 3] = v.w;
  }

  const float4* src = (const float4*)(cb + ((size_t)k0 << 6));
  for (int i = threadIdx.x; i < 2048; i += 256) sc[i] = src[i];
  if (threadIdx.x < 128) scc[threadIdx.x] = cc[k0 + threadIdx.x];
  __syncthreads();

  // zz = sum z^2, numpy pairwise-8 order, unfused
  float r[8];
#pragma unroll
  for (int j = 0; j < 8; ++j) r[j] = __fmul_rn(z[j], z[j]);
#pragma unroll
  for (int bb = 1; bb < 8; ++bb)
#pragma unroll
    for (int j = 0; j < 8; ++j)
      r[j] = __fadd_rn(r[j], __fmul_rn(z[bb * 8 + j], z[bb * 8 + j]));
  float zz = __fadd_rn(__fadd_rn(__fadd_rn(r[0], r[1]), __fadd_rn(r[2], r[3])),
                       __fadd_rn(__fadd_rn(r[4], r[5]), __fadd_rn(r[6], r[7])));

  float4 w0[4], w1[4], w2[4], w3[4];
#pragma unroll
  for (int j = 0; j < 4; ++j) { w0[j] = sc[j]; w1[j] = sc[4 + j]; w2[j] = sc[8 + j]; w3[j] = sc[12 + j]; }
  float ccc = scc[0];

  float best = 3.4e38f;
  int bidx = k0;
#pragma unroll 1
  for (int kk = 0; kk < 128; ++kk) {
    int nk = (kk + 1) & 127;
    const float4* nx = sc + (nk << 4);
    float ccn = scc[nk];
    float d0 = 0.f, d1 = 0.f, d2 = 0.f, d3 = 0.f;
    SRCH_Q(w0, 0)  SRCH_L(w0, 0)
    SRCH_Q(w1, 16) SRCH_L(w1, 4)
    SRCH_Q(w2, 32) SRCH_L(w2, 8)
    SRCH_Q(w3, 48) SRCH_L(w3, 12)
    float dot = (d0 + d1) + (d2 + d3);
    float dist = __fadd_rn(__fadd_rn(zz, ccc), -2.0f * dot);
    if (dist < best) { best = dist; bidx = k0 + kk; }   // strict < : first-min
    ccc = ccn;
  }
  bestb[(size_t)p * 4 + q] = best;
  bidxb[(size_t)p * 4 + q] = bidx;
}

// --- combine: reduce 4 chunk minima in ascending-chunk order, then
// loss partial + histogram + indices. (unchanged)
__global__ __launch_bounds__(256) void vq_combine(const float* __restrict__ zbuf,
                                                  const float* __restrict__ cb,
                                                  const float* __restrict__ bestb,
                                                  const int* __restrict__ bidxb,
                                                  float* __restrict__ outIdx,
                                                  int* __restrict__ wsIdx,
                                                  float* __restrict__ lossAcc,
                                                  unsigned int* __restrict__ hist) {
  int p = blockIdx.x * 256 + threadIdx.x;
  float4 bq = ((const float4*)bestb)[p];
  int4 iq = ((const int4*)bidxb)[p];
  float best = bq.x; int bidx = iq.x;
  if (bq.y < best) { best = bq.y; bidx = iq.y; }
  if (bq.z < best) { best = bq.z; bidx = iq.z; }
  if (bq.w < best) { best = bq.w; bidx = iq.w; }

  const float4* q4 = (const float4*)(cb + (bidx << 6));
  const float4* z4 = (const float4*)(zbuf + (size_t)p * 64);
  float ls = 0.f;
#pragma unroll
  for (int i = 0; i < 16; ++i) {
    float4 qv = q4[i];
    float4 zv = z4[i];
    float e;
    e = __fsub_rn(qv.x, zv.x); ls = fmaf(e, e, ls);
    e = __fsub_rn(qv.y, zv.y); ls = fmaf(e, e, ls);
    e = __fsub_rn(qv.z, zv.z); ls = fmaf(e, e, ls);
    e = __fsub_rn(qv.w, zv.w); ls = fmaf(e, e, ls);
  }
#pragma unroll
  for (int off = 32; off; off >>= 1) ls += __shfl_xor(ls, off, 64);
  if ((threadIdx.x & 63) == 0) atomicAdd(lossAcc, ls);
  atomicAdd(&hist[bidx], 1u);
  wsIdx[p] = bidx;
  outIdx[p] = (float)bidx;
}

// ===================== vq_decode =====================
// out[b,o,hw] = sum_d q[d]*postW[o,d] + postB[o]; o split in 4 chunks of 32
// (grid 2048). postW chunk staged in LDS, quarter-row pipeline like search.

#define DEC_Q(WB, ZOFF) { \
  _Pragma("unroll") \
  for (int j = 0; j < 4; ++j) { \
    float4 c4 = WB[j]; \
    a0 = fmaf(qv[(ZOFF) + 4*j + 0], c4.x, a0); \
    a1 = fmaf(qv[(ZOFF) + 4*j + 1], c4.y, a1); \
    a2 = fmaf(qv[(ZOFF) + 4*j + 2], c4.z, a2); \
    a3 = fmaf(qv[(ZOFF) + 4*j + 3], c4.w, a3); } }

#define DEC_L(WB, OFF) { \
  _Pragma("unroll") \
  for (int j = 0; j < 4; ++j) WB[j] = nx[(OFF) + j]; }

__global__ __launch_bounds__(256) void vq_decode(const float* __restrict__ cb,
                                                 const int* __restrict__ wsIdx,
                                                 const float* __restrict__ postW,
                                                 const float* __restrict__ postB,
                                                 float* __restrict__ dec) {
  __shared__ float4 sw[512];    // 32 rows * 16 f4 = 8 KB
  __shared__ float spb[32];
  int bid = blockIdx.x;
  int och = bid & 3, ph = bid >> 2;
  int o0 = och << 5;
  int p = ph * 256 + threadIdx.x;
  int b = p >> 12, hw = p & 4095;
  int k = wsIdx[p];

  // gather quantized row (codebook is L1/L2-hot) — issue early
  float qv[64];
  const float4* q4 = (const float4*)(cb + (k << 6));
#pragma unroll
  for (int i = 0; i < 16; ++i) {
    float4 v = q4[i];
    qv[4 * i + 0] = v.x; qv[4 * i + 1] = v.y; qv[4 * i + 2] = v.z; qv[4 * i + 3] = v.w;
  }

  const float4* wsrc = (const float4*)(postW + ((size_t)o0 << 6));
  for (int i = threadIdx.x; i < 512; i += 256) sw[i] = wsrc[i];
  if (threadIdx.x < 32) spb[threadIdx.x] = postB[o0 + threadIdx.x];
  __syncthreads();

  float4 W0[4], W1[4], W2[4], W3[4];
#pragma unroll
  for (int j = 0; j < 4; ++j) { W0[j] = sw[j]; W1[j] = sw[4 + j]; W2[j] = sw[8 + j]; W3[j] = sw[12 + j]; }
  float pbc = spb[0];

  float* out = dec + (size_t)b * CHN * HWN + hw;
#pragma unroll 1
  for (int oo = 0; oo < 32; ++oo) {
    int no = (oo + 1) & 31;
    const float4* nx = sw + (no << 4);
    float pbn = spb[no];
    float a0 = 0.f, a1 = 0.f, a2 = 0.f, a3 = 0.f;
    DEC_Q(W0, 0)  DEC_L(W0, 0)
    DEC_Q(W1, 16) DEC_L(W1, 4)
    DEC_Q(W2, 32) DEC_L(W2, 8)
    DEC_Q(W3, 48) DEC_L(W3, 12)
    out[(size_t)(o0 + oo) * HWN] = ((a0 + a1) + (a2 + a3)) + pbc;  // coalesced
    pbc = pbn;
  }
}

// --- finalize: loss scalar + perplexity (unchanged)
__global__ __launch_bounds__(512) void vq_final(const unsigned int* __restrict__ hist,
                                                const float* __restrict__ lossAcc,
                                                float* __restrict__ outLoss,
                                                float* __restrict__ outPerp) {
  __shared__ float sred[8];
  int t = threadIdx.x;
  float c = (float)hist[t];
  float pavg = c * (1.0f / 131072.0f);
  float term = pavg * logf(pavg + 1e-10f);
#pragma unroll
  for (int off = 32; off; off >>= 1) term += __shfl_xor(term, off, 64);
  if ((t & 63) == 0) sred[t >> 6] = term;
  __syncthreads();
  if (t == 0) {
    float s = 0.f;
    for (int i = 0; i < 8; ++i) s += sred[i];
    *outPerp = expf(-s);
    *outLoss = 1.25f * (*lossAcc) * (1.0f / 8388608.0f);
  }
}

extern "C" void kernel_launch(void* const* d_in, const int* in_sizes, int n_in,
                              void* d_out, int out_size, void* d_ws, size_t ws_size,
                              hipStream_t stream) {
  const float* A     = (const float*)d_in[0];
  const float* preW  = (const float*)d_in[1];
  const float* preB  = (const float*)d_in[2];
  const float* cb    = (const float*)d_in[3];
  const float* postW = (const float*)d_in[4];
  const float* postB = (const float*)d_in[5];
  float* out = (float*)d_out;

  char* ws = (char*)d_ws;
  unsigned int* hist = (unsigned int*)(ws + WS_HIST);
  float* lossAcc = (float*)(ws + WS_LOSS);
  float* cc      = (float*)(ws + WS_CC);
  float* preWT   = (float*)(ws + WS_PWT);
  int* wsIdx     = (int*)(ws + WS_IDX);

  // scratch inside the decode-output region (overwritten by vq_decode last)
  float* zbuf  = out + 8;                    // 16B-aligned
  float* bestb = out + 8388616;
  int*   bidxb = (int*)(out + 8912904);

  hipMemsetAsync(ws, 0, 2052, stream);  // zero hist + loss accumulator
  vq_prep<<<1, 512, 0, stream>>>(preW, cb, preWT, cc);
  vq_pre<<<1024, 256, 0, stream>>>(A, preWT, preB, zbuf);
  vq_search<<<2048, 256, 0, stream>>>(zbuf, cb, cc, bestb, bidxb);
  vq_combine<<<512, 256, 0, stream>>>(zbuf, cb, bestb, bidxb,
                                      out + 16777218, wsIdx, lossAcc, hist);
  vq_decode<<<2048, 256, 0, stream>>>(cb, wsIdx, postW, postB, out + 1);
  vq_final<<<1, 512, 0, stream>>>(hist, lossAcc, out, out + 16777217);
}

// Round 5
// 441.093 us; speedup vs baseline: 1.3576x; 1.3576x over previous
//
#include <hip/hip_runtime.h>

typedef unsigned short u16;
typedef unsigned int u32;
typedef __attribute__((ext_vector_type(8))) short short8v;   // 8 bf16 (4 VGPRs)
typedef __attribute__((ext_vector_type(4))) float f32x4;

// Problem constants
#define NPX   131072      // B*H*W = 32*64*64 pixels
#define CHN   128         // NUM_HIDDENS
#define HWN   4096        // H*W
#define EMB   64
#define NCODE 512

// ws layout (bytes)
#define WS_HIST 0         // 512 * u32
#define WS_LOSS 2048      // 1 * f32
#define WS_CC   4096      // 512 * f32
#define WS_PWT  8192      // 128*64 f32 (pre_w transposed, 32 KB)
#define WS_IDX  40960     // 131072 * i32 (512 KB)

// Scratch carved out of the decode-output region (out+1 .. out+16777216),
// fully overwritten by vq_decode at the end. Byte offsets from `out`:
//   zh : 32        .. 16777248   (131072*64 u16 — bf16 hi split of z)
//   zm : 16777248  .. 33554464   (mid split)
//   zl : 33554464  .. 50331680   (lo split; zh+zm+zl == z bitwise)
//   zz : 50331680  .. 50855968   (131072 f32, exact pairwise-8 sum z^2)
//   ch : 50855968  .. 50921504   (512*64 u16 — codebook hi split)
//   cm : 50921504  .. 50987040
//   cl : 50987040  .. 51052576   (< 67,108,876 bytes, inside decode region)

#define MFMA(a, b, c) __builtin_amdgcn_mfma_f32_16x16x32_bf16((a), (b), (c), 0, 0, 0)

// exact aligned-truncation 3-way split of fp32 into bf16 parts
#define SPLIT3(V, HH, MM, LL) {                          \
  u32 zb_ = __float_as_uint(V);                          \
  HH = zb_ >> 16;                                        \
  float fh_ = __uint_as_float(HH << 16);                 \
  float r1_ = __fsub_rn((V), fh_);                       \
  MM = __float_as_uint(r1_) >> 16;                       \
  float fm_ = __uint_as_float(MM << 16);                 \
  float r2_ = __fsub_rn(r1_, fm_);                       \
  LL = __float_as_uint(r2_) >> 16; }

__device__ __forceinline__ float rec3(u32 hb, u32 mb, u32 lb) {
  // exact reconstruction: non-overlapping mantissa slices
  return __fadd_rn(__fadd_rn(__uint_as_float(hb), __uint_as_float(mb)),
                   __uint_as_float(lb));
}

// --- prep: transpose pre_w to [c][d]; cc[k] = sum_d cb[k][d]^2 (pairwise-8);
//     bf16 3-way splits of codebook rows.
__global__ __launch_bounds__(512) void vq_prep(const float* __restrict__ preW,
                                               const float* __restrict__ cb,
                                               float* __restrict__ preWT,
                                               float* __restrict__ cc,
                                               u16* __restrict__ ch,
                                               u16* __restrict__ cm,
                                               u16* __restrict__ cl) {
  int t = threadIdx.x;
  for (int i = t; i < CHN * EMB; i += 512) {
    int c = i >> 6, d = i & 63;
    preWT[i] = preW[d * CHN + c];   // preW is [64][128]
  }
  if (t < NCODE) {
    const float* row = cb + t * EMB;
    float r[8];
#pragma unroll
    for (int j = 0; j < 8; ++j) r[j] = __fmul_rn(row[j], row[j]);
#pragma unroll
    for (int b = 1; b < 8; ++b)
#pragma unroll
      for (int j = 0; j < 8; ++j)
        r[j] = __fadd_rn(r[j], __fmul_rn(row[b * 8 + j], row[b * 8 + j]));
    cc[t] = __fadd_rn(__fadd_rn(__fadd_rn(r[0], r[1]), __fadd_rn(r[2], r[3])),
                      __fadd_rn(__fadd_rn(r[4], r[5]), __fadd_rn(r[6], r[7])));
    for (int d = 0; d < EMB; ++d) {
      float v = row[d];
      u32 hh, mm, ll;
      SPLIT3(v, hh, mm, ll)
      ch[t * EMB + d] = (u16)hh;
      cm[t * EMB + d] = (u16)mm;
      cl[t * EMB + d] = (u16)ll;
    }
  }
}

// ===================== vq_pre =====================
// z[p][d] = sum_c A[b,c,hw]*preW[d,c] + preB[d], d split in halves (grid 1024).
// Identical arithmetic to the round-1 passing version; epilogue writes the
// exact bf16 3-way split of z instead of fp32 z.
__global__ __launch_bounds__(256) void vq_pre(const float* __restrict__ A,
                                              const float* __restrict__ preWT,
                                              const float* __restrict__ preB,
                                              u16* __restrict__ zh,
                                              u16* __restrict__ zm,
                                              u16* __restrict__ zl) {
  int bid = blockIdx.x;
  int ph = bid & 511, dh = bid >> 9;     // dh in {0,1}
  int d0 = dh << 5;
  int p = ph * 256 + threadIdx.x;
  int b = p >> 12, hw = p & 4095;
  const float* Ab = A + (size_t)b * CHN * HWN + hw;

  float z[32];
#pragma unroll
  for (int d = 0; d < 32; ++d) z[d] = 0.f;
  for (int c = 0; c < CHN; c += 4) {
    float a0 = Ab[(size_t)(c + 0) * HWN];   // coalesced, 4-deep prefetch
    float a1 = Ab[(size_t)(c + 1) * HWN];
    float a2 = Ab[(size_t)(c + 2) * HWN];
    float a3 = Ab[(size_t)(c + 3) * HWN];
    const float* w = preWT + c * EMB + d0;  // wave-uniform -> s_load
#pragma unroll
    for (int d = 0; d < 32; ++d) z[d] = __fadd_rn(z[d], __fmul_rn(a0, w[d]));
    w += EMB;
#pragma unroll
    for (int d = 0; d < 32; ++d) z[d] = __fadd_rn(z[d], __fmul_rn(a1, w[d]));
    w += EMB;
#pragma unroll
    for (int d = 0; d < 32; ++d) z[d] = __fadd_rn(z[d], __fmul_rn(a2, w[d]));
    w += EMB;
#pragma unroll
    for (int d = 0; d < 32; ++d) z[d] = __fadd_rn(z[d], __fmul_rn(a3, w[d]));
  }
#pragma unroll
  for (int d = 0; d < 32; ++d) z[d] = __fadd_rn(z[d], preB[d0 + d]);

  // exact split + packed stores (16 words per split)
  u32 hwd[16], mwd[16], lwd[16];
#pragma unroll
  for (int i = 0; i < 32; ++i) {
    u32 hh, mm, ll;
    SPLIT3(z[i], hh, mm, ll)
    int wdi = i >> 1;
    if ((i & 1) == 0) { hwd[wdi] = hh; mwd[wdi] = mm; lwd[wdi] = ll; }
    else { hwd[wdi] |= hh << 16; mwd[wdi] |= mm << 16; lwd[wdi] |= ll << 16; }
  }
  size_t rowo = (size_t)p * 64 + d0;   // u16 index
  uint4* dh4 = (uint4*)(zh + rowo);
  uint4* dm4 = (uint4*)(zm + rowo);
  uint4* dl4 = (uint4*)(zl + rowo);
#pragma unroll
  for (int q = 0; q < 4; ++q) {
    dh4[q] = make_uint4(hwd[4 * q], hwd[4 * q + 1], hwd[4 * q + 2], hwd[4 * q + 3]);
    dm4[q] = make_uint4(mwd[4 * q], mwd[4 * q + 1], mwd[4 * q + 2], mwd[4 * q + 3]);
    dl4[q] = make_uint4(lwd[4 * q], lwd[4 * q + 1], lwd[4 * q + 2], lwd[4 * q + 3]);
  }
}

// ===================== vq_zz =====================
// zz[p] = sum z^2 in the exact numpy pairwise-8 order, from the exact splits.
__global__ __launch_bounds__(256) void vq_zz(const u16* __restrict__ zh,
                                             const u16* __restrict__ zm,
                                             const u16* __restrict__ zl,
                                             float* __restrict__ zz) {
  int p = blockIdx.x * 256 + threadIdx.x;
  const uint4* ph = (const uint4*)(zh + (size_t)p * 64);
  const uint4* pm = (const uint4*)(zm + (size_t)p * 64);
  const uint4* pl = (const uint4*)(zl + (size_t)p * 64);
  float r[8];
#pragma unroll
  for (int bb = 0; bb < 8; ++bb) {
    uint4 h4 = ph[bb], m4 = pm[bb], l4 = pl[bb];
    float zv[8];
    zv[0] = rec3(h4.x << 16, m4.x << 16, l4.x << 16);
    zv[1] = rec3(h4.x & 0xffff0000u, m4.x & 0xffff0000u, l4.x & 0xffff0000u);
    zv[2] = rec3(h4.y << 16, m4.y << 16, l4.y << 16);
    zv[3] = rec3(h4.y & 0xffff0000u, m4.y & 0xffff0000u, l4.y & 0xffff0000u);
    zv[4] = rec3(h4.z << 16, m4.z << 16, l4.z << 16);
    zv[5] = rec3(h4.z & 0xffff0000u, m4.z & 0xffff0000u, l4.z & 0xffff0000u);
    zv[6] = rec3(h4.w << 16, m4.w << 16, l4.w << 16);
    zv[7] = rec3(h4.w & 0xffff0000u, m4.w & 0xffff0000u, l4.w & 0xffff0000u);
#pragma unroll
    for (int j = 0; j < 8; ++j) {
      float sq = __fmul_rn(zv[j], zv[j]);
      r[j] = (bb == 0) ? sq : __fadd_rn(r[j], sq);
    }
  }
  zz[p] = __fadd_rn(__fadd_rn(__fadd_rn(r[0], r[1]), __fadd_rn(r[2], r[3])),
                    __fadd_rn(__fadd_rn(r[4], r[5]), __fadd_rn(r[6], r[7])));
}

// ===================== vq_search (MFMA) =====================
// dot[p][k] via 8 bf16-split passes on 16x16x32 MFMA; dist = fl(fl(zz+cc)-2dot);
// lexicographic (dist, k) min == reference first-min argmin.
// Per wave: M=64 pixels (4 tiles), loop 32 N-tiles over all 512 codes.

#define LOADB(S, T) {                                                   \
  int kr_ = ((T) & 31) * 16 + mcol;                                     \
  size_t ob_ = (size_t)kr_ * 64 + g8;                                   \
  S##h0 = *(const short8v*)(ch + ob_); S##h1 = *(const short8v*)(ch + ob_ + 32); \
  S##m0 = *(const short8v*)(cm + ob_); S##m1 = *(const short8v*)(cm + ob_ + 32); \
  S##l0 = *(const short8v*)(cl + ob_); S##l1 = *(const short8v*)(cl + ob_ + 32); }

#define COMP(S, T) {                                                    \
  float ccv_ = scc[((T) << 4) + mcol];                                  \
  _Pragma("unroll")                                                     \
  for (int mt = 0; mt < 4; ++mt) {                                      \
    f32x4 acc = {0.f, 0.f, 0.f, 0.f};                                   \
    acc = MFMA(Ah[mt][0], S##h0, acc); acc = MFMA(Ah[mt][1], S##h1, acc); \
    acc = MFMA(Am[mt][0], S##h0, acc); acc = MFMA(Am[mt][1], S##h1, acc); \
    acc = MFMA(Ah[mt][0], S##m0, acc); acc = MFMA(Ah[mt][1], S##m1, acc); \
    acc = MFMA(Am[mt][0], S##m0, acc); acc = MFMA(Am[mt][1], S##m1, acc); \
    acc = MFMA(Al[mt][0], S##h0, acc); acc = MFMA(Al[mt][1], S##h1, acc); \
    acc = MFMA(Ah[mt][0], S##l0, acc); acc = MFMA(Ah[mt][1], S##l1, acc); \
    acc = MFMA(Al[mt][0], S##m0, acc); acc = MFMA(Al[mt][1], S##m1, acc); \
    acc = MFMA(Am[mt][0], S##l0, acc); acc = MFMA(Am[mt][1], S##l1, acc); \
    _Pragma("unroll")                                                   \
    for (int r = 0; r < 4; ++r) {                                       \
      float dist_ = __fadd_rn(__fadd_rn(zzr[mt][r], ccv_), -2.0f * acc[r]); \
      if (dist_ < best[mt][r]) { best[mt][r] = dist_; bidx[mt][r] = ((T) << 4) + mcol; } \
    } } }

__global__ __launch_bounds__(256, 2) void vq_search(const u16* __restrict__ zh,
                                                    const u16* __restrict__ zm,
                                                    const u16* __restrict__ zl,
                                                    const u16* __restrict__ ch,
                                                    const u16* __restrict__ cm,
                                                    const u16* __restrict__ cl,
                                                    const float* __restrict__ cc,
                                                    const float* __restrict__ zz,
                                                    int* __restrict__ wsIdx) {
  __shared__ float scc[512];
  int tid = threadIdx.x;
  scc[tid] = cc[tid];
  scc[tid + 256] = cc[tid + 256];
  __syncthreads();

  int lane = tid & 63, wid = tid >> 6;
  int Mbase = blockIdx.x * 256 + wid * 64;
  int mcol = lane & 15, g = lane >> 4;
  size_t g8 = (size_t)(g * 8);

  // A fragments: 4 M-tiles x 2 K-tiles x 3 splits (loaded once)
  short8v Ah[4][2], Am[4][2], Al[4][2];
#pragma unroll
  for (int mt = 0; mt < 4; ++mt) {
    size_t rz = (size_t)(Mbase + mt * 16 + mcol) * 64 + g8;
    Ah[mt][0] = *(const short8v*)(zh + rz); Ah[mt][1] = *(const short8v*)(zh + rz + 32);
    Am[mt][0] = *(const short8v*)(zm + rz); Am[mt][1] = *(const short8v*)(zm + rz + 32);
    Al[mt][0] = *(const short8v*)(zl + rz); Al[mt][1] = *(const short8v*)(zl + rz + 32);
  }
  // zz for the 16 pixel slots this lane owns (row = 4g+r within each M-tile)
  float zzr[4][4];
#pragma unroll
  for (int mt = 0; mt < 4; ++mt)
#pragma unroll
    for (int r = 0; r < 4; ++r)
      zzr[mt][r] = zz[Mbase + mt * 16 + g * 4 + r];

  float best[4][4];
  int bidx[4][4];
#pragma unroll
  for (int mt = 0; mt < 4; ++mt)
#pragma unroll
    for (int r = 0; r < 4; ++r) { best[mt][r] = 3.4e38f; bidx[mt][r] = 0; }

  // B double-buffer (named regs, static indexing only)
  short8v PAh0, PAh1, PAm0, PAm1, PAl0, PAl1;
  short8v PBh0, PBh1, PBm0, PBm1, PBl0, PBl1;
  LOADB(PA, 0)
#pragma unroll 1
  for (int t2 = 0; t2 < 16; ++t2) {
    int t = t2 * 2;
    LOADB(PB, t + 1)
    COMP(PA, t)
    LOADB(PA, t + 2)   // wraps to tile 0 at the end (unused)
    COMP(PB, t + 1)
  }

  // cross-lane lexicographic (dist, k) min within each 16-lane column group
#pragma unroll
  for (int mt = 0; mt < 4; ++mt)
#pragma unroll
    for (int r = 0; r < 4; ++r) {
      float v = best[mt][r];
      int ix = bidx[mt][r];
#pragma unroll
      for (int off = 1; off < 16; off <<= 1) {
        float ov = __shfl_xor(v, off, 64);
        int oi = __shfl_xor(ix, off, 64);
        if (ov < v || (ov == v && oi < ix)) { v = ov; ix = oi; }
      }
      if (mcol == 0) wsIdx[Mbase + mt * 16 + g * 4 + r] = ix;
    }
}

// ===================== vq_combine =====================
// loss partial (exact z reconstruction, identical chain) + histogram + indices.
__global__ __launch_bounds__(256) void vq_combine(const u16* __restrict__ zh,
                                                  const u16* __restrict__ zm,
                                                  const u16* __restrict__ zl,
                                                  const float* __restrict__ cb,
                                                  const int* __restrict__ wsIdx,
                                                  float* __restrict__ outIdx,
                                                  float* __restrict__ lossAcc,
                                                  unsigned int* __restrict__ hist) {
  int p = blockIdx.x * 256 + threadIdx.x;
  int k = wsIdx[p];
  const float4* q4 = (const float4*)(cb + (k << 6));
  const uint4* ph = (const uint4*)(zh + (size_t)p * 64);
  const uint4* pm = (const uint4*)(zm + (size_t)p * 64);
  const uint4* pl = (const uint4*)(zl + (size_t)p * 64);
  float ls = 0.f;
#pragma unroll
  for (int bb = 0; bb < 8; ++bb) {
    uint4 h4 = ph[bb], m4 = pm[bb], l4 = pl[bb];
    float4 qa = q4[2 * bb], qb = q4[2 * bb + 1];
    float z0 = rec3(h4.x << 16, m4.x << 16, l4.x << 16);
    float z1 = rec3(h4.x & 0xffff0000u, m4.x & 0xffff0000u, l4.x & 0xffff0000u);
    float z2 = rec3(h4.y << 16, m4.y << 16, l4.y << 16);
    float z3 = rec3(h4.y & 0xffff0000u, m4.y & 0xffff0000u, l4.y & 0xffff0000u);
    float z4v = rec3(h4.z << 16, m4.z << 16, l4.z << 16);
    float z5 = rec3(h4.z & 0xffff0000u, m4.z & 0xffff0000u, l4.z & 0xffff0000u);
    float z6 = rec3(h4.w << 16, m4.w << 16, l4.w << 16);
    float z7 = rec3(h4.w & 0xffff0000u, m4.w & 0xffff0000u, l4.w & 0xffff0000u);
    float e;
    e = __fsub_rn(qa.x, z0); ls = fmaf(e, e, ls);
    e = __fsub_rn(qa.y, z1); ls = fmaf(e, e, ls);
    e = __fsub_rn(qa.z, z2); ls = fmaf(e, e, ls);
    e = __fsub_rn(qa.w, z3); ls = fmaf(e, e, ls);
    e = __fsub_rn(qb.x, z4v); ls = fmaf(e, e, ls);
    e = __fsub_rn(qb.y, z5); ls = fmaf(e, e, ls);
    e = __fsub_rn(qb.z, z6); ls = fmaf(e, e, ls);
    e = __fsub_rn(qb.w, z7); ls = fmaf(e, e, ls);
  }
#pragma unroll
  for (int off = 32; off; off >>= 1) ls += __shfl_xor(ls, off, 64);
  if ((threadIdx.x & 63) == 0) atomicAdd(lossAcc, ls);
  atomicAdd(&hist[k], 1u);
  outIdx[p] = (float)k;
}

// ===================== vq_decode (round-1 verbatim) =====================
__global__ __launch_bounds__(256) void vq_decode(const float* __restrict__ cb,
                                                 const int* __restrict__ wsIdx,
                                                 const float* __restrict__ postW,
                                                 const float* __restrict__ postB,
                                                 float* __restrict__ dec) {
  int bid = blockIdx.x;
  int och = bid & 3, ph = bid >> 2;
  int o0 = och << 5;
  int p = ph * 256 + threadIdx.x;
  int b = p >> 12, hw = p & 4095;
  int k = wsIdx[p];
  float q[64];
  const float4* q4 = (const float4*)(cb + (k << 6));
#pragma unroll
  for (int i = 0; i < 16; ++i) {
    float4 v = q4[i];
    q[4 * i + 0] = v.x; q[4 * i + 1] = v.y; q[4 * i + 2] = v.z; q[4 * i + 3] = v.w;
  }
  float* out = dec + (size_t)b * CHN * HWN + hw;
  for (int o = o0; o < o0 + 32; ++o) {
    const float* w = postW + o * EMB;       // wave-uniform -> s_load
    float a0 = 0.f, a1 = 0.f, a2 = 0.f, a3 = 0.f;
#pragma unroll
    for (int dd = 0; dd < 64; dd += 4) {
      a0 = fmaf(q[dd + 0], w[dd + 0], a0);
      a1 = fmaf(q[dd + 1], w[dd + 1], a1);
      a2 = fmaf(q[dd + 2], w[dd + 2], a2);
      a3 = fmaf(q[dd + 3], w[dd + 3], a3);
    }
    out[(size_t)o * HWN] = ((a0 + a1) + (a2 + a3)) + postB[o];  // coalesced per o
  }
}

// --- finalize: loss scalar + perplexity (unchanged)
__global__ __launch_bounds__(512) void vq_final(const unsigned int* __restrict__ hist,
                                                const float* __restrict__ lossAcc,
                                                float* __restrict__ outLoss,
                                                float* __restrict__ outPerp) {
  __shared__ float sred[8];
  int t = threadIdx.x;
  float c = (float)hist[t];
  float pavg = c * (1.0f / 131072.0f);
  float term = pavg * logf(pavg + 1e-10f);
#pragma unroll
  for (int off = 32; off; off >>= 1) term += __shfl_xor(term, off, 64);
  if ((t & 63) == 0) sred[t >> 6] = term;
  __syncthreads();
  if (t == 0) {
    float s = 0.f;
    for (int i = 0; i < 8; ++i) s += sred[i];
    *outPerp = expf(-s);
    *outLoss = 1.25f * (*lossAcc) * (1.0f / 8388608.0f);
  }
}

extern "C" void kernel_launch(void* const* d_in, const int* in_sizes, int n_in,
                              void* d_out, int out_size, void* d_ws, size_t ws_size,
                              hipStream_t stream) {
  const float* A     = (const float*)d_in[0];
  const float* preW  = (const float*)d_in[1];
  const float* preB  = (const float*)d_in[2];
  const float* cb    = (const float*)d_in[3];
  const float* postW = (const float*)d_in[4];
  const float* postB = (const float*)d_in[5];
  float* out = (float*)d_out;

  char* ws = (char*)d_ws;
  unsigned int* hist = (unsigned int*)(ws + WS_HIST);
  float* lossAcc = (float*)(ws + WS_LOSS);
  float* cc      = (float*)(ws + WS_CC);
  float* preWT   = (float*)(ws + WS_PWT);
  int* wsIdx     = (int*)(ws + WS_IDX);

  // scratch inside the decode-output region (overwritten by vq_decode last)
  char* outc = (char*)d_out;
  u16*   zh = (u16*)(outc + 32);
  u16*   zm = (u16*)(outc + 16777248);
  u16*   zl = (u16*)(outc + 33554464);
  float* zz = (float*)(outc + 50331680);
  u16*   ch = (u16*)(outc + 50855968);
  u16*   cm = (u16*)(outc + 50921504);
  u16*   cl = (u16*)(outc + 50987040);

  hipMemsetAsync(ws, 0, 2052, stream);  // zero hist + loss accumulator
  vq_prep<<<1, 512, 0, stream>>>(preW, cb, preWT, cc, ch, cm, cl);
  vq_pre<<<1024, 256, 0, stream>>>(A, preWT, preB, zh, zm, zl);
  vq_zz<<<512, 256, 0, stream>>>(zh, zm, zl, zz);
  vq_search<<<512, 256, 0, stream>>>(zh, zm, zl, ch, cm, cl, cc, zz, wsIdx);
  vq_combine<<<512, 256, 0, stream>>>(zh, zm, zl, cb, wsIdx,
                                      out + 16777218, lossAcc, hist);
  vq_decode<<<2048, 256, 0, stream>>>(cb, wsIdx, postW, postB, out + 1);
  vq_final<<<1, 512, 0, stream>>>(hist, lossAcc, out, out + 16777217);
}

// Round 6
// 320.242 us; speedup vs baseline: 1.8699x; 1.3774x over previous
//
#include <hip/hip_runtime.h>

typedef unsigned short u16;
typedef unsigned int u32;
typedef __attribute__((ext_vector_type(8))) short short8v;   // 8 bf16 (4 VGPRs)
typedef __attribute__((ext_vector_type(4))) float f32x4;

// Problem constants
#define NPX   131072      // B*H*W = 32*64*64 pixels
#define CHN   128         // NUM_HIDDENS
#define HWN   4096        // H*W
#define EMB   64
#define NCODE 512

// ws layout (bytes) — total 565,248 (known-safe extent from round 0/1)
#define WS_HIST 0         // 512 * u32
#define WS_LOSS 2048      // 1 * f32
#define WS_CC   4096      // 512 * f32
#define WS_PWT  8192      // 128*64 f32 (pre_w transposed, 32 KB)
#define WS_IDX  40960     // 131072 * u16 (256 KB) -> ends 303104
#define WS_DT   303104    // 512*128 f32 decode table (256 KB) -> ends 565248

// out-region scratch (overwritten by vq_decode last). Byte offsets from out:
//   zh 32..16777248, zm 16777248..33554464, zl 33554464..50331680 (tiled splits)
//   zz 50331680..50855968 (f32)
//   ch 50855968..50921504, cm ..50987040, cl ..51052576 (tiled cb splits)
//
// MFMA-tiled layout (u16 units), elem (row r, col d):
//   idx = (r>>4)*1024 + (d>>3)*128 + (r&15)*8 + (d&7)
// -> search fragment load for lane l in tile T: u16 addr T*1024 + l*8 (+512)
//    = perfectly lane-linear 16B/lane; pre stores 16B chunks at (r&15)*16 B
//    within 256B runs = full-sector writes.

#define MFMA(a, b, c) __builtin_amdgcn_mfma_f32_16x16x32_bf16((a), (b), (c), 0, 0, 0)

// exact aligned-truncation 3-way split of fp32 into bf16 parts
#define SPLIT3(V, HH, MM, LL) {                          \
  u32 zb_ = __float_as_uint(V);                          \
  HH = zb_ >> 16;                                        \
  float fh_ = __uint_as_float(HH << 16);                 \
  float r1_ = __fsub_rn((V), fh_);                       \
  MM = __float_as_uint(r1_) >> 16;                       \
  float fm_ = __uint_as_float(MM << 16);                 \
  float r2_ = __fsub_rn(r1_, fm_);                       \
  LL = __float_as_uint(r2_) >> 16; }

__device__ __forceinline__ float rec3(u32 hb, u32 mb, u32 lb) {
  return __fadd_rn(__fadd_rn(__uint_as_float(hb), __uint_as_float(mb)),
                   __uint_as_float(lb));
}

// --- prep: transpose pre_w; cc[k] (pairwise-8); tiled codebook splits.
__global__ __launch_bounds__(512) void vq_prep(const float* __restrict__ preW,
                                               const float* __restrict__ cb,
                                               float* __restrict__ preWT,
                                               float* __restrict__ cc,
                                               u16* __restrict__ ch,
                                               u16* __restrict__ cm,
                                               u16* __restrict__ cl) {
  int t = threadIdx.x;
  for (int i = t; i < CHN * EMB; i += 512) {
    int c = i >> 6, d = i & 63;
    preWT[i] = preW[d * CHN + c];   // preW is [64][128]
  }
  if (t < NCODE) {
    const float* row = cb + t * EMB;
    float r[8];
#pragma unroll
    for (int j = 0; j < 8; ++j) r[j] = __fmul_rn(row[j], row[j]);
#pragma unroll
    for (int b = 1; b < 8; ++b)
#pragma unroll
      for (int j = 0; j < 8; ++j)
        r[j] = __fadd_rn(r[j], __fmul_rn(row[b * 8 + j], row[b * 8 + j]));
    cc[t] = __fadd_rn(__fadd_rn(__fadd_rn(r[0], r[1]), __fadd_rn(r[2], r[3])),
                      __fadd_rn(__fadd_rn(r[4], r[5]), __fadd_rn(r[6], r[7])));
    int tile = t >> 4, rr = t & 15;
    for (int d = 0; d < EMB; ++d) {
      float v = row[d];
      u32 hh, mm, ll;
      SPLIT3(v, hh, mm, ll)
      size_t ti = (size_t)tile * 1024 + (size_t)(d >> 3) * 128 + rr * 8 + (d & 7);
      ch[ti] = (u16)hh;
      cm[ti] = (u16)mm;
      cl[ti] = (u16)ll;
    }
  }
}

// --- dtab: DT[k][o] = fl(dot(cb[k], postW[o]) + postB[o]) — same fmaf-quad
// chain as the previously-passing decode (bitwise-equal values).
__global__ __launch_bounds__(256) void vq_dtab(const float* __restrict__ cb,
                                               const float* __restrict__ postW,
                                               const float* __restrict__ postB,
                                               float* __restrict__ DT) {
  int idx = blockIdx.x * 256 + threadIdx.x;   // grid 256 -> 65536 = 512*128
  int k = idx >> 7, o = idx & 127;
  const float* q = cb + k * EMB;              // wave-uniform -> s_load
  const float* w = postW + o * EMB;
  float a0 = 0.f, a1 = 0.f, a2 = 0.f, a3 = 0.f;
#pragma unroll
  for (int dd = 0; dd < 64; dd += 4) {
    a0 = fmaf(q[dd + 0], w[dd + 0], a0);
    a1 = fmaf(q[dd + 1], w[dd + 1], a1);
    a2 = fmaf(q[dd + 2], w[dd + 2], a2);
    a3 = fmaf(q[dd + 3], w[dd + 3], a3);
  }
  DT[(size_t)k * 128 + o] = ((a0 + a1) + (a2 + a3)) + postB[o];
}

// ===================== vq_pre =====================
// Identical arithmetic chain to the round-5 passing version (sequential c,
// unfused mul+add, d-halves across blocks); ONLY the store addresses change
// to the MFMA-tiled layout (full-sector coalesced writes).
__global__ __launch_bounds__(256) void vq_pre(const float* __restrict__ A,
                                              const float* __restrict__ preWT,
                                              const float* __restrict__ preB,
                                              u16* __restrict__ zh,
                                              u16* __restrict__ zm,
                                              u16* __restrict__ zl) {
  int bid = blockIdx.x;
  int ph = bid & 511, dh = bid >> 9;     // dh in {0,1}
  int d0 = dh << 5;
  int p = ph * 256 + threadIdx.x;
  int b = p >> 12, hw = p & 4095;
  const float* Ab = A + (size_t)b * CHN * HWN + hw;

  float z[32];
#pragma unroll
  for (int d = 0; d < 32; ++d) z[d] = 0.f;
  for (int c = 0; c < CHN; c += 4) {
    float a0 = Ab[(size_t)(c + 0) * HWN];   // coalesced, 4-deep prefetch
    float a1 = Ab[(size_t)(c + 1) * HWN];
    float a2 = Ab[(size_t)(c + 2) * HWN];
    float a3 = Ab[(size_t)(c + 3) * HWN];
    const float* w = preWT + c * EMB + d0;  // wave-uniform -> s_load
#pragma unroll
    for (int d = 0; d < 32; ++d) z[d] = __fadd_rn(z[d], __fmul_rn(a0, w[d]));
    w += EMB;
#pragma unroll
    for (int d = 0; d < 32; ++d) z[d] = __fadd_rn(z[d], __fmul_rn(a1, w[d]));
    w += EMB;
#pragma unroll
    for (int d = 0; d < 32; ++d) z[d] = __fadd_rn(z[d], __fmul_rn(a2, w[d]));
    w += EMB;
#pragma unroll
    for (int d = 0; d < 32; ++d) z[d] = __fadd_rn(z[d], __fmul_rn(a3, w[d]));
  }
#pragma unroll
  for (int d = 0; d < 32; ++d) z[d] = __fadd_rn(z[d], preB[d0 + d]);

  // exact split + packed stores; word group q = elems d0+8q..d0+8q+7
  u32 hwd[16], mwd[16], lwd[16];
#pragma unroll
  for (int i = 0; i < 32; ++i) {
    u32 hh, mm, ll;
    SPLIT3(z[i], hh, mm, ll)
    int wdi = i >> 1;
    if ((i & 1) == 0) { hwd[wdi] = hh; mwd[wdi] = mm; lwd[wdi] = ll; }
    else { hwd[wdi] |= hh << 16; mwd[wdi] |= mm << 16; lwd[wdi] |= ll << 16; }
  }
  int tile = p >> 4, rr = p & 15;
  size_t base = (size_t)tile * 1024 + (size_t)(dh * 4) * 128 + rr * 8;
#pragma unroll
  for (int q = 0; q < 4; ++q) {
    size_t off = base + (size_t)q * 128;
    *(uint4*)(zh + off) = make_uint4(hwd[4*q], hwd[4*q+1], hwd[4*q+2], hwd[4*q+3]);
    *(uint4*)(zm + off) = make_uint4(mwd[4*q], mwd[4*q+1], mwd[4*q+2], mwd[4*q+3]);
    *(uint4*)(zl + off) = make_uint4(lwd[4*q], lwd[4*q+1], lwd[4*q+2], lwd[4*q+3]);
  }
}

// ===================== vq_zz =====================
// zz[p] = sum z^2, exact numpy pairwise-8 order, from the exact tiled splits.
__global__ __launch_bounds__(256) void vq_zz(const u16* __restrict__ zh,
                                             const u16* __restrict__ zm,
                                             const u16* __restrict__ zl,
                                             float* __restrict__ zz) {
  int p = blockIdx.x * 256 + threadIdx.x;
  int tile = p >> 4, rr = p & 15;
  size_t base = (size_t)tile * 1024 + rr * 8;
  float r[8];
#pragma unroll
  for (int bb = 0; bb < 8; ++bb) {
    size_t off = base + (size_t)bb * 128;
    uint4 h4 = *(const uint4*)(zh + off);
    uint4 m4 = *(const uint4*)(zm + off);
    uint4 l4 = *(const uint4*)(zl + off);
    float zv[8];
    zv[0] = rec3(h4.x << 16, m4.x << 16, l4.x << 16);
    zv[1] = rec3(h4.x & 0xffff0000u, m4.x & 0xffff0000u, l4.x & 0xffff0000u);
    zv[2] = rec3(h4.y << 16, m4.y << 16, l4.y << 16);
    zv[3] = rec3(h4.y & 0xffff0000u, m4.y & 0xffff0000u, l4.y & 0xffff0000u);
    zv[4] = rec3(h4.z << 16, m4.z << 16, l4.z << 16);
    zv[5] = rec3(h4.z & 0xffff0000u, m4.z & 0xffff0000u, l4.z & 0xffff0000u);
    zv[6] = rec3(h4.w << 16, m4.w << 16, l4.w << 16);
    zv[7] = rec3(h4.w & 0xffff0000u, m4.w & 0xffff0000u, l4.w & 0xffff0000u);
#pragma unroll
    for (int j = 0; j < 8; ++j) {
      float sq = __fmul_rn(zv[j], zv[j]);
      r[j] = (bb == 0) ? sq : __fadd_rn(r[j], sq);
    }
  }
  zz[p] = __fadd_rn(__fadd_rn(__fadd_rn(r[0], r[1]), __fadd_rn(r[2], r[3])),
                    __fadd_rn(__fadd_rn(r[4], r[5]), __fadd_rn(r[6], r[7])));
}

// ===================== vq_search (MFMA, tiled coalesced fragments) ==========
// Same 8-pass split MFMA + lexicographic (dist,k) min as the round-5 passing
// version; only fragment addressing changed (lane-linear tiled loads).

#define LOADB(S, T) {                                                   \
  size_t ob_ = (size_t)((T) & 31) * 1024 + l8;                          \
  S##h0 = *(const short8v*)(ch + ob_); S##h1 = *(const short8v*)(ch + ob_ + 512); \
  S##m0 = *(const short8v*)(cm + ob_); S##m1 = *(const short8v*)(cm + ob_ + 512); \
  S##l0 = *(const short8v*)(cl + ob_); S##l1 = *(const short8v*)(cl + ob_ + 512); }

#define COMP(S, T) {                                                    \
  float ccv_ = scc[((T) << 4) + mcol];                                  \
  _Pragma("unroll")                                                     \
  for (int mt = 0; mt < 4; ++mt) {                                      \
    f32x4 acc = {0.f, 0.f, 0.f, 0.f};                                   \
    acc = MFMA(Ah[mt][0], S##h0, acc); acc = MFMA(Ah[mt][1], S##h1, acc); \
    acc = MFMA(Am[mt][0], S##h0, acc); acc = MFMA(Am[mt][1], S##h1, acc); \
    acc = MFMA(Ah[mt][0], S##m0, acc); acc = MFMA(Ah[mt][1], S##m1, acc); \
    acc = MFMA(Am[mt][0], S##m0, acc); acc = MFMA(Am[mt][1], S##m1, acc); \
    acc = MFMA(Al[mt][0], S##h0, acc); acc = MFMA(Al[mt][1], S##h1, acc); \
    acc = MFMA(Ah[mt][0], S##l0, acc); acc = MFMA(Ah[mt][1], S##l1, acc); \
    acc = MFMA(Al[mt][0], S##m0, acc); acc = MFMA(Al[mt][1], S##m1, acc); \
    acc = MFMA(Am[mt][0], S##l0, acc); acc = MFMA(Am[mt][1], S##l1, acc); \
    _Pragma("unroll")                                                   \
    for (int r = 0; r < 4; ++r) {                                       \
      float dist_ = __fadd_rn(__fadd_rn(zzr[mt][r], ccv_), -2.0f * acc[r]); \
      if (dist_ < best[mt][r]) { best[mt][r] = dist_; bidx[mt][r] = ((T) << 4) + mcol; } \
    } } }

__global__ __launch_bounds__(256, 2) void vq_search(const u16* __restrict__ zh,
                                                    const u16* __restrict__ zm,
                                                    const u16* __restrict__ zl,
                                                    const u16* __restrict__ ch,
                                                    const u16* __restrict__ cm,
                                                    const u16* __restrict__ cl,
                                                    const float* __restrict__ cc,
                                                    const float* __restrict__ zz,
                                                    u16* __restrict__ wsIdx) {
  __shared__ float scc[512];
  int tid = threadIdx.x;
  scc[tid] = cc[tid];
  scc[tid + 256] = cc[tid + 256];
  __syncthreads();

  int lane = tid & 63, wid = tid >> 6;
  int Mbase = blockIdx.x * 256 + wid * 64;
  int mcol = lane & 15, g = lane >> 4;
  size_t l8 = (size_t)lane * 8;

  // A fragments: tiled lane-linear loads (coalesced 1KB/instr)
  short8v Ah[4][2], Am[4][2], Al[4][2];
#pragma unroll
  for (int mt = 0; mt < 4; ++mt) {
    size_t tz = (size_t)((Mbase >> 4) + mt) * 1024 + l8;
    Ah[mt][0] = *(const short8v*)(zh + tz); Ah[mt][1] = *(const short8v*)(zh + tz + 512);
    Am[mt][0] = *(const short8v*)(zm + tz); Am[mt][1] = *(const short8v*)(zm + tz + 512);
    Al[mt][0] = *(const short8v*)(zl + tz); Al[mt][1] = *(const short8v*)(zl + tz + 512);
  }
  float zzr[4][4];
#pragma unroll
  for (int mt = 0; mt < 4; ++mt)
#pragma unroll
    for (int r = 0; r < 4; ++r)
      zzr[mt][r] = zz[Mbase + mt * 16 + g * 4 + r];

  float best[4][4];
  int bidx[4][4];
#pragma unroll
  for (int mt = 0; mt < 4; ++mt)
#pragma unroll
    for (int r = 0; r < 4; ++r) { best[mt][r] = 3.4e38f; bidx[mt][r] = 0; }

  short8v PAh0, PAh1, PAm0, PAm1, PAl0, PAl1;
  short8v PBh0, PBh1, PBm0, PBm1, PBl0, PBl1;
  LOADB(PA, 0)
#pragma unroll 1
  for (int t2 = 0; t2 < 16; ++t2) {
    int t = t2 * 2;
    LOADB(PB, t + 1)
    COMP(PA, t)
    LOADB(PA, t + 2)   // wraps to tile 0 at the end (unused)
    COMP(PB, t + 1)
  }

  // cross-lane lexicographic (dist, k) min == first-min argmin
#pragma unroll
  for (int mt = 0; mt < 4; ++mt)
#pragma unroll
    for (int r = 0; r < 4; ++r) {
      float v = best[mt][r];
      int ix = bidx[mt][r];
#pragma unroll
      for (int off = 1; off < 16; off <<= 1) {
        float ov = __shfl_xor(v, off, 64);
        int oi = __shfl_xor(ix, off, 64);
        if (ov < v || (ov == v && oi < ix)) { v = ov; ix = oi; }
      }
      if (mcol == 0) wsIdx[Mbase + mt * 16 + g * 4 + r] = (u16)ix;
    }
}

// ===================== vq_combine =====================
// loss partial (exact z reconstruction, identical chain) + histogram + indices.
__global__ __launch_bounds__(256) void vq_combine(const u16* __restrict__ zh,
                                                  const u16* __restrict__ zm,
                                                  const u16* __restrict__ zl,
                                                  const float* __restrict__ cb,
                                                  const u16* __restrict__ wsIdx,
                                                  float* __restrict__ outIdx,
                                                  float* __restrict__ lossAcc,
                                                  unsigned int* __restrict__ hist) {
  int p = blockIdx.x * 256 + threadIdx.x;
  int k = wsIdx[p];
  const float4* q4 = (const float4*)(cb + (k << 6));
  int tile = p >> 4, rr = p & 15;
  size_t base = (size_t)tile * 1024 + rr * 8;
  float ls = 0.f;
#pragma unroll
  for (int bb = 0; bb < 8; ++bb) {
    size_t off = base + (size_t)bb * 128;
    uint4 h4 = *(const uint4*)(zh + off);
    uint4 m4 = *(const uint4*)(zm + off);
    uint4 l4 = *(const uint4*)(zl + off);
    float4 qa = q4[2 * bb], qb = q4[2 * bb + 1];
    float z0 = rec3(h4.x << 16, m4.x << 16, l4.x << 16);
    float z1 = rec3(h4.x & 0xffff0000u, m4.x & 0xffff0000u, l4.x & 0xffff0000u);
    float z2 = rec3(h4.y << 16, m4.y << 16, l4.y << 16);
    float z3 = rec3(h4.y & 0xffff0000u, m4.y & 0xffff0000u, l4.y & 0xffff0000u);
    float z4v = rec3(h4.z << 16, m4.z << 16, l4.z << 16);
    float z5 = rec3(h4.z & 0xffff0000u, m4.z & 0xffff0000u, l4.z & 0xffff0000u);
    float z6 = rec3(h4.w << 16, m4.w << 16, l4.w << 16);
    float z7 = rec3(h4.w & 0xffff0000u, m4.w & 0xffff0000u, l4.w & 0xffff0000u);
    float e;
    e = __fsub_rn(qa.x, z0); ls = fmaf(e, e, ls);
    e = __fsub_rn(qa.y, z1); ls = fmaf(e, e, ls);
    e = __fsub_rn(qa.z, z2); ls = fmaf(e, e, ls);
    e = __fsub_rn(qa.w, z3); ls = fmaf(e, e, ls);
    e = __fsub_rn(qb.x, z4v); ls = fmaf(e, e, ls);
    e = __fsub_rn(qb.y, z5); ls = fmaf(e, e, ls);
    e = __fsub_rn(qb.z, z6); ls = fmaf(e, e, ls);
    e = __fsub_rn(qb.w, z7); ls = fmaf(e, e, ls);
  }
#pragma unroll
  for (int off = 32; off; off >>= 1) ls += __shfl_xor(ls, off, 64);
  if ((threadIdx.x & 63) == 0) atomicAdd(lossAcc, ls);
  atomicAdd(&hist[k], 1u);
  outIdx[p] = (float)k;
}

// ===================== vq_decode (gather from DT) =====================
// out[b,o,hw] = DT[k_p][o] — bitwise-equal to recomputing the fmaf-quad dot
// per pixel (DT built with the identical chain). Write-roofline bound.
__global__ __launch_bounds__(256) void vq_decode(const u16* __restrict__ wsIdx,
                                                 const float* __restrict__ DT,
                                                 float* __restrict__ dec) {
  int p = blockIdx.x * 256 + threadIdx.x;
  int b = p >> 12, hw = p & 4095;
  int k = wsIdx[p];
  const float4* Dk = (const float4*)(DT + (size_t)k * 128);   // L2-hot 512B row
  float* out = dec + (size_t)b * CHN * HWN + hw;
#pragma unroll 4
  for (int oq = 0; oq < 32; ++oq) {
    float4 v = Dk[oq];
    out[(size_t)(4 * oq + 0) * HWN] = v.x;   // coalesced per o
    out[(size_t)(4 * oq + 1) * HWN] = v.y;
    out[(size_t)(4 * oq + 2) * HWN] = v.z;
    out[(size_t)(4 * oq + 3) * HWN] = v.w;
  }
}

// --- finalize: loss scalar + perplexity (unchanged)
__global__ __launch_bounds__(512) void vq_final(const unsigned int* __restrict__ hist,
                                                const float* __restrict__ lossAcc,
                                                float* __restrict__ outLoss,
                                                float* __restrict__ outPerp) {
  __shared__ float sred[8];
  int t = threadIdx.x;
  float c = (float)hist[t];
  float pavg = c * (1.0f / 131072.0f);
  float term = pavg * logf(pavg + 1e-10f);
#pragma unroll
  for (int off = 32; off; off >>= 1) term += __shfl_xor(term, off, 64);
  if ((t & 63) == 0) sred[t >> 6] = term;
  __syncthreads();
  if (t == 0) {
    float s = 0.f;
    for (int i = 0; i < 8; ++i) s += sred[i];
    *outPerp = expf(-s);
    *outLoss = 1.25f * (*lossAcc) * (1.0f / 8388608.0f);
  }
}

extern "C" void kernel_launch(void* const* d_in, const int* in_sizes, int n_in,
                              void* d_out, int out_size, void* d_ws, size_t ws_size,
                              hipStream_t stream) {
  const float* A     = (const float*)d_in[0];
  const float* preW  = (const float*)d_in[1];
  const float* preB  = (const float*)d_in[2];
  const float* cb    = (const float*)d_in[3];
  const float* postW = (const float*)d_in[4];
  const float* postB = (const float*)d_in[5];
  float* out = (float*)d_out;

  char* ws = (char*)d_ws;
  unsigned int* hist = (unsigned int*)(ws + WS_HIST);
  float* lossAcc = (float*)(ws + WS_LOSS);
  float* cc      = (float*)(ws + WS_CC);
  float* preWT   = (float*)(ws + WS_PWT);
  u16* wsIdx     = (u16*)(ws + WS_IDX);
  float* DT      = (float*)(ws + WS_DT);

  // scratch inside the decode-output region (overwritten by vq_decode last)
  char* outc = (char*)d_out;
  u16*   zh = (u16*)(outc + 32);
  u16*   zm = (u16*)(outc + 16777248);
  u16*   zl = (u16*)(outc + 33554464);
  float* zz = (float*)(outc + 50331680);
  u16*   ch = (u16*)(outc + 50855968);
  u16*   cm = (u16*)(outc + 50921504);
  u16*   cl = (u16*)(outc + 50987040);

  hipMemsetAsync(ws, 0, 2052, stream);  // zero hist + loss accumulator
  vq_prep<<<1, 512, 0, stream>>>(preW, cb, preWT, cc, ch, cm, cl);
  vq_dtab<<<256, 256, 0, stream>>>(cb, postW, postB, DT);
  vq_pre<<<1024, 256, 0, stream>>>(A, preWT, preB, zh, zm, zl);
  vq_zz<<<512, 256, 0, stream>>>(zh, zm, zl, zz);
  vq_search<<<512, 256, 0, stream>>>(zh, zm, zl, ch, cm, cl, cc, zz, wsIdx);
  vq_combine<<<512, 256, 0, stream>>>(zh, zm, zl, cb, wsIdx,
                                      out + 16777218, lossAcc, hist);
  vq_decode<<<512, 256, 0, stream>>>(wsIdx, DT, out + 1);
  vq_final<<<1, 512, 0, stream>>>(hist, lossAcc, out, out + 16777217);
}